// Round 9
// baseline (2895.716 us; speedup 1.0000x reference)
//
#include <hip/hip_runtime.h>
#include <stdint.h>

// Problem constants (fixed by setup_inputs)
constexpr int Bn = 32, Cc = 24, Hh = 28, Ww = 28;
constexpr int OHt = 24, OWt = 24;           // output spatial
constexpr int CF = 600, HN = 128, TT = 96;  // channels-folded, hidden, spikes
constexpr int NPIX = OHt * OWt;             // 576
constexpr int NSAMP = Bn * TT * NPIX;       // 1,769,472
constexpr int NLOG = Bn * Cc * Hh * Ww;     // 602,112

// ---- JAX threefry2x32, key(42) -> (0, 42), partitionable counter mode ----
// Caller pre-adds the ks1=42 key injection: pass x1 = counter + 42.
__device__ __forceinline__ uint32_t threefry_0_42_pre(uint32_t x1) {
  const uint32_t ks1 = 42u, ks2 = 0x1BD11BF0u;  // 0x1BD11BDA ^ 0 ^ 42
  uint32_t x0 = x1;                                      // 0 + x1
  x1 = __builtin_rotateleft32(x1, 13) ^ x0;
  x0 += x1; x1 = __builtin_rotateleft32(x1, 15) ^ x0;
  x0 += x1; x1 = __builtin_rotateleft32(x1, 26) ^ x0;
  x0 += x1; x1 = __builtin_rotateleft32(x1,  6) ^ x0;
  x0 += ks1; x1 += ks2 + 1u;
  x0 += x1; x1 = __builtin_rotateleft32(x1, 17) ^ x0;
  x0 += x1; x1 = __builtin_rotateleft32(x1, 29) ^ x0;
  x0 += x1; x1 = __builtin_rotateleft32(x1, 16) ^ x0;
  x0 += x1; x1 = __builtin_rotateleft32(x1, 24) ^ x0;
  x0 += ks2; x1 += 2u;
  x0 += x1; x1 = __builtin_rotateleft32(x1, 13) ^ x0;
  x0 += x1; x1 = __builtin_rotateleft32(x1, 15) ^ x0;
  x0 += x1; x1 = __builtin_rotateleft32(x1, 26) ^ x0;
  x0 += x1; x1 = __builtin_rotateleft32(x1,  6) ^ x0;
  x1 += ks1 + 3u;
  x0 += x1; x1 = __builtin_rotateleft32(x1, 17) ^ x0;
  x0 += x1; x1 = __builtin_rotateleft32(x1, 29) ^ x0;
  x0 += x1; x1 = __builtin_rotateleft32(x1, 16) ^ x0;
  x0 += x1; x1 = __builtin_rotateleft32(x1, 24) ^ x0;
  x0 += ks1; x1 += ks2 + 4u;
  x0 += x1; x1 = __builtin_rotateleft32(x1, 13) ^ x0;
  x0 += x1; x1 = __builtin_rotateleft32(x1, 15) ^ x0;
  x0 += x1; x1 = __builtin_rotateleft32(x1, 26) ^ x0;
  x0 += x1; x1 = __builtin_rotateleft32(x1,  6) ^ x0;
  x0 += ks2; x1 += 5u;
  return x0 ^ x1;
}

// rinc[i] = 2^-23 / in[i]. in is U(0.01, 1) by setup -> rinc finite, > 0.
__global__ __launch_bounds__(256) void k_rinc(const float* __restrict__ in,
                                              float* __restrict__ rc) {
  int i = blockIdx.x * 256 + threadIdx.x;
  if (i < NLOG) rc[i] = 1.1920928955078125e-7f / in[i];  // 0x1p-23 / in
}

// Cold path: full bit-exact first-max-wins rescan of one sample, computing
// lp = logf(in) on the fly (same ocml logf the reference/XLA uses; identical
// to the lp array all prior passing kernels staged).
__device__ __attribute__((noinline)) int exact_argmax(
    uint32_t base, const float* __restrict__ inb) {
  float best = -1e30f;
  int bi = 0;
  int cf = 0;
  #pragma unroll 1
  for (int c = 0; c < Cc; ++c) {
    const float* inc = inb + c * (Hh * Ww);
    #pragma unroll 1
    for (int ki = 0; ki < 5; ++ki)
      #pragma unroll
      for (int kj = 0; kj < 5; ++kj) {
        uint32_t bits = threefry_0_42_pre(base + (uint32_t)cf);
        uint32_t key = bits >> 9;
        float f = __uint_as_float(key | 0x3f800000u) - 1.0f;
        float u = (f == 0.0f) ? 1.17549435e-38f : f;  // max(tiny, f)
        float l1 = logf(u);
        float v = -logf(-l1) + logf(inc[ki * Ww + kj]);
        if (v > best) { best = v; bi = cf; }  // strict >: first-max-wins
        ++cf;
      }
  }
  return bi;
}

// ---- Branchless exact-order surrogate (round-8 core) ----
// Identity (exact, no near-1 approx): e^{-v} = (-ln u) / in  with
// u = key*2^-23 = 1 - T, T = (2^23-key)*2^-23. So argmax v == argmin R,
// R = -ln(1-T)/in. Surrogate: Rh = (T + T^2/2 + T^3/3)/in, computed as
// (rinc*tailf) * (1 + T/2 + T^2/3) -- 8 full-rate VALU, no trans, no branch.
// One-sided: poly <= -ln(1-T) for T in [0,1) => Rh <= R*(1+1e-6) ALWAYS.
// Two-sided: |Rh/R - 1| <= T^3/4 + eps <= 3.5e-5 whenever T <= 0.05.
// Track min1/min2 of packed = (bits(Rh) & ~1023) | cf (positive-float bit
// order == float order; low-10-bit clear = downward quantization <= 2^-13
// rel; cf tiebreak picks LOWEST cf = first-max-wins).
// Resolve: confident iff f1 <= 0.04 (=> T_best <= Rh*(1+eps) <= 0.0401 =>
// two-sided bound applies to the winner) AND f2 > f1*(1+2^-10) (margin
// 9.8e-4 >> quant 1.3e-4 + series 3.5e-5 + 2x ocml-vs-true-math 2e-6).
// All others j have R_j >= Rh_j/(1+1e-6) >= f2*(1-1e-6) via the
// ALWAYS-valid one-sided bound. Else: rare (~1e-3/sample) exact rescan.
// Edge key=0 (u=tiny in reference): Rh = 1.833/in >= 1.833 > 0.04 ->
// never confident -> exact rescan handles it. Sound.
__global__ __launch_bounds__(256) void k_sample(const float* __restrict__ rincp,
                                                const float* __restrict__ input,
                                                int* __restrict__ spikes) {
  int tid = blockIdx.x * 256 + threadIdx.x;  // [0, NSAMP/2)
  int y = tid % OWt;
  int x = (tid / OWt) % OHt;
  int t = (tid / NPIX) % 48;
  int b = tid / (NPIX * 48);
  int sid1 = ((b * TT + t) * OHt + x) * OWt + y;
  // sample 2 = sid1 + 48*NPIX; counter stride = 48*NPIX*600 = 16,588,800
  uint32_t ctr1 = (uint32_t)sid1 * 600u + 42u;  // ks1 pre-added
  const float* rcb = rincp + (b * Cc) * (Hh * Ww) + x * Ww + y;

  uint32_t m1a = 0xFFFFFFFFu, m2a = 0xFFFFFFFFu;  // sample 1 min1/min2
  uint32_t m1b = 0xFFFFFFFFu, m2b = 0xFFFFFFFFu;  // sample 2 min1/min2

#define SURR(BITS, RC, M1, M2)                                              \
  {                                                                         \
    uint32_t key = (BITS) >> 9;                                             \
    float tailf = (float)(0x800000u - key);       /* exact, <= 2^23 */      \
    float s = (RC)*tailf;                         /* T / in */              \
    float T = tailf * 1.1920928955078125e-7f;     /* tail * 2^-23 */        \
    float q = __builtin_fmaf(                                               \
        T, __builtin_fmaf(T, 0.33333333333f, 0.5f), 1.0f);                  \
    float rh = s * q;                                                       \
    uint32_t pk = (__float_as_uint(rh) & 0xFFFFFC00u) | (uint32_t)cf;       \
    uint32_t tmp = (pk > M1) ? pk : M1;           /* max */                 \
    M2 = (M2 < tmp) ? M2 : tmp;                   /* min */                 \
    M1 = (M1 < pk) ? M1 : pk;                     /* min */                 \
  }

  int cf = 0;
  #pragma unroll 1
  for (int c = 0; c < Cc; ++c) {
    const float* rcc = rcb + c * (Hh * Ww);
    #pragma unroll
    for (int ki = 0; ki < 5; ++ki) {
      #pragma unroll
      for (int kj = 0; kj < 5; ++kj) {
        float rc = rcc[ki * Ww + kj];
        uint32_t c1 = ctr1 + (uint32_t)cf;
        uint32_t bb1 = threefry_0_42_pre(c1);
        uint32_t bb2 = threefry_0_42_pre(c1 + 16588800u);
        SURR(bb1, rc, m1a, m2a)
        SURR(bb2, rc, m1b, m2b)
        ++cf;
      }
    }
  }
#undef SURR

  // Resolve both samples.
  const float* inb = input + (b * Cc) * (Hh * Ww) + x * Ww + y;
  float f1a = __uint_as_float(m1a & 0xFFFFFC00u);
  float f2a = __uint_as_float(m2a & 0xFFFFFC00u);
  float f1b = __uint_as_float(m1b & 0xFFFFFC00u);
  float f2b = __uint_as_float(m2b & 0xFFFFFC00u);
  constexpr float MARG = 1.0f + 0.0009765625f;  // 1 + 2^-10
  bool ca = (f1a <= 0.04f) && (f2a > f1a * MARG);
  bool cb = (f1b <= 0.04f) && (f2b > f1b * MARG);
  spikes[sid1] = ca ? (int)(m1a & 1023u) : exact_argmax(ctr1, inb);
  spikes[sid1 + 48 * NPIX] =
      cb ? (int)(m1b & 1023u) : exact_argmax(ctr1 + 16588800u, inb);
}

// One wave per pixel, 2 neurons per lane; 96 sequential normalized updates.
__global__ __launch_bounds__(256) void k_recur(
    const int* __restrict__ spikes, const float* __restrict__ weights,
    const float* __restrict__ eps_xy, const float* __restrict__ eps_t,
    const float* __restrict__ eps0p, const float* __restrict__ h_init,
    float* __restrict__ out) {
  int wid = blockIdx.x * 4 + (threadIdx.x >> 6);  // pixel id in [0, 18432)
  int lane = threadIdx.x & 63;
  int y = wid % OWt;
  int x = (wid / OWt) % OHt;
  int b = wid / NPIX;
  float g0 = h_init[lane];
  float g1 = h_init[lane + 64];
  float e0 = eps0p[0];
  const int* sp = spikes + (b * TT) * NPIX + x * OWt + y;
  const float* ex = eps_xy + (x * OWt + y) * 25;
  for (int t = 0; t < TT; ++t) {
    int s = sp[t * NPIX];  // wave-uniform
    const float* wr = weights + s * HN;
    float wg0 = wr[lane] * g0;
    float wg1 = wr[lane + 64] * g1;
    float sum = wg0 + wg1;
    #pragma unroll
    for (int off = 32; off > 0; off >>= 1) sum += __shfl_xor(sum, off, 64);
    float es = ex[s % 25] * (eps_t[t] * e0);  // eps * (et * eps0)
    float factor = es / sum;
    if (!__builtin_isfinite(factor)) factor = 0.0f;  // nan_to_num
    float d = 1.0f + es;
    g0 = (g0 + wg0 * factor) / d;
    g1 = (g1 + wg1 * factor) / d;
  }
  out[((b * HN + lane) * OHt + x) * OWt + y] = g0;
  out[((b * HN + lane + 64) * OHt + x) * OWt + y] = g1;
}

extern "C" void kernel_launch(void* const* d_in, const int* in_sizes, int n_in,
                              void* d_out, int out_size, void* d_ws, size_t ws_size,
                              hipStream_t stream) {
  const float* input   = (const float*)d_in[0];
  const float* eps_xy  = (const float*)d_in[1];
  const float* eps0    = (const float*)d_in[2];
  const float* eps_t   = (const float*)d_in[3];
  const float* weights = (const float*)d_in[4];
  const float* h_init  = (const float*)d_in[5];
  // d_in[6] = number_of_spikes (=96, hardcoded)

  float* rinc = (float*)d_ws;                                // 602,112 f32
  int* spikes = (int*)((char*)d_ws + NLOG * sizeof(float));  // 1,769,472 i32

  k_rinc<<<(NLOG + 255) / 256, 256, 0, stream>>>(input, rinc);
  k_sample<<<(NSAMP / 2) / 256, 256, 0, stream>>>(rinc, input, spikes);
  k_recur<<<(Bn * NPIX) / 4, 256, 0, stream>>>(spikes, weights, eps_xy, eps_t,
                                               eps0, h_init, (float*)d_out);
}

// Round 10
// 2322.509 us; speedup vs baseline: 1.2468x; 1.2468x over previous
//
#include <hip/hip_runtime.h>
#include <stdint.h>

// Problem constants (fixed by setup_inputs)
constexpr int Bn = 32, Cc = 24, Hh = 28, Ww = 28;
constexpr int OHt = 24, OWt = 24;           // output spatial
constexpr int CF = 600, HN = 128, TT = 96;  // channels-folded, hidden, spikes
constexpr int NPIX = OHt * OWt;             // 576
constexpr int NSAMP = Bn * TT * NPIX;       // 1,769,472
constexpr int NLOG = Bn * Cc * Hh * Ww;     // 602,112
constexpr int QCAP = 16384;                 // ambiguous-queue capacity (~9 sigma)
constexpr int NOUT = Bn * HN * NPIX;        // 2,359,296 floats in d_out

// ---- JAX threefry2x32, key(42) -> (0, 42), partitionable counter mode ----
// Caller pre-adds the ks1=42 key injection: pass x1 = counter + 42.
__device__ __forceinline__ uint32_t threefry_0_42_pre(uint32_t x1) {
  const uint32_t ks1 = 42u, ks2 = 0x1BD11BF0u;  // 0x1BD11BDA ^ 0 ^ 42
  uint32_t x0 = x1;                                      // 0 + x1
  x1 = __builtin_rotateleft32(x1, 13) ^ x0;
  x0 += x1; x1 = __builtin_rotateleft32(x1, 15) ^ x0;
  x0 += x1; x1 = __builtin_rotateleft32(x1, 26) ^ x0;
  x0 += x1; x1 = __builtin_rotateleft32(x1,  6) ^ x0;
  x0 += ks1; x1 += ks2 + 1u;
  x0 += x1; x1 = __builtin_rotateleft32(x1, 17) ^ x0;
  x0 += x1; x1 = __builtin_rotateleft32(x1, 29) ^ x0;
  x0 += x1; x1 = __builtin_rotateleft32(x1, 16) ^ x0;
  x0 += x1; x1 = __builtin_rotateleft32(x1, 24) ^ x0;
  x0 += ks2; x1 += 2u;
  x0 += x1; x1 = __builtin_rotateleft32(x1, 13) ^ x0;
  x0 += x1; x1 = __builtin_rotateleft32(x1, 15) ^ x0;
  x0 += x1; x1 = __builtin_rotateleft32(x1, 26) ^ x0;
  x0 += x1; x1 = __builtin_rotateleft32(x1,  6) ^ x0;
  x1 += ks1 + 3u;
  x0 += x1; x1 = __builtin_rotateleft32(x1, 17) ^ x0;
  x0 += x1; x1 = __builtin_rotateleft32(x1, 29) ^ x0;
  x0 += x1; x1 = __builtin_rotateleft32(x1, 16) ^ x0;
  x0 += x1; x1 = __builtin_rotateleft32(x1, 24) ^ x0;
  x0 += ks1; x1 += ks2 + 4u;
  x0 += x1; x1 = __builtin_rotateleft32(x1, 13) ^ x0;
  x0 += x1; x1 = __builtin_rotateleft32(x1, 15) ^ x0;
  x0 += x1; x1 = __builtin_rotateleft32(x1, 26) ^ x0;
  x0 += x1; x1 = __builtin_rotateleft32(x1,  6) ^ x0;
  x0 += ks2; x1 += 5u;
  return x0 ^ x1;
}

// rinc[i] = 2^-23 / in[i]; also zero the ambiguous-queue counter.
__global__ __launch_bounds__(256) void k_rinc(const float* __restrict__ in,
                                              float* __restrict__ rc,
                                              int* __restrict__ qcount) {
  int i = blockIdx.x * 256 + threadIdx.x;
  if (i == 0) *qcount = 0;
  if (i < NLOG) rc[i] = 1.1920928955078125e-7f / in[i];  // 0x1p-23 / in
}

// Exact value (bit-identical to the reference / all prior passing kernels).
__device__ __forceinline__ float exact_v(uint32_t bits, float lp) {
  uint32_t key = bits >> 9;
  float f = __uint_as_float(key | 0x3f800000u) - 1.0f;
  float u = (f == 0.0f) ? 1.17549435e-38f : f;  // max(tiny, f)
  float l1 = logf(u);
  return -logf(-l1) + lp;
}

// Safety valve (QCAP overflow only; P ~ 0): serial bit-exact rescan.
__device__ __attribute__((noinline)) int exact_argmax_serial(
    uint32_t base, const float* __restrict__ inb) {
  float best = -1e30f;
  int bi = 0;
  int cf = 0;
  #pragma unroll 1
  for (int c = 0; c < Cc; ++c) {
    const float* inc = inb + c * (Hh * Ww);
    #pragma unroll 1
    for (int ki = 0; ki < 5; ++ki)
      #pragma unroll
      for (int kj = 0; kj < 5; ++kj) {
        float v = exact_v(threefry_0_42_pre(base + (uint32_t)cf),
                          logf(inc[ki * Ww + kj]));
        if (v > best) { best = v; bi = cf; }  // strict >: first-max-wins
        ++cf;
      }
  }
  return bi;
}

// ---- Branchless exact-order surrogate (r8 math, r10 structure) ----
// Identity (exact): e^{-v} = (-ln u)/in, u = key*2^-23 = 1 - T,
// T = (2^23-key)*2^-23. argmax v == argmin R, R = -ln(1-T)/in.
// Surrogate Rh = (rinc*tailf)*(1 + T/2 + T^2/3): 8 full-rate VALU, no trans,
// no branch. One-sided: Rh <= R*(1+1e-6) ALWAYS. Two-sided: |Rh/R-1| <=
// 3.5e-5 when T <= 0.05. Track min1/min2 of pk = (bits(Rh)&~1023)|cf
// (positive-float bit order == value order; quantization <= 2^-13 rel,
// downward; cf tiebreak = lowest cf = first-max-wins).
// Confident iff f1 <= 0.04 (winner in two-sided zone; P(f1>0.04)=e^-12)
// AND f2 > f1*(1+2^-10) (margin 9.8e-4 >> quant 1.3e-4 + series 3.5e-5 +
// 2x ocml-vs-math 2e-6). Ambiguous (~1e-3/sample): queue for k_fix.
__global__ __launch_bounds__(256, 8) void k_sample(
    const float* __restrict__ rincp, const float* __restrict__ input,
    int* __restrict__ spikes, int* __restrict__ qcount,
    int* __restrict__ queue) {
  int tid = blockIdx.x * 256 + threadIdx.x;  // [0, NSAMP/2)
  int y = tid % OWt;
  int x = (tid / OWt) % OHt;
  int t = (tid / NPIX) % 48;
  int b = tid / (NPIX * 48);
  int sid1 = ((b * TT + t) * OHt + x) * OWt + y;
  // sample 2 = sid1 + 48*NPIX; counter stride = 48*NPIX*600 = 16,588,800
  uint32_t ctr1 = (uint32_t)sid1 * 600u + 42u;  // ks1 pre-added
  const float* rcb = rincp + (b * Cc) * (Hh * Ww) + x * Ww + y;

  uint32_t m1a = 0xFFFFFFFFu, m2a = 0xFFFFFFFFu;  // sample 1 min1/min2
  uint32_t m1b = 0xFFFFFFFFu, m2b = 0xFFFFFFFFu;  // sample 2 min1/min2

#define SURR(BITS, RC, M1, M2)                                              \
  {                                                                         \
    uint32_t key = (BITS) >> 9;                                             \
    float tailf = (float)(0x800000u - key);       /* exact, in [1,2^23] */  \
    float s = (RC)*tailf;                         /* T / in */              \
    float T = tailf * 1.1920928955078125e-7f;     /* tail * 2^-23 */        \
    float q = __builtin_fmaf(                                               \
        T, __builtin_fmaf(T, 0.33333333333f, 0.5f), 1.0f);                  \
    float rh = s * q;                                                       \
    uint32_t pk = (__float_as_uint(rh) & 0xFFFFFC00u) | (uint32_t)cf;       \
    uint32_t tmp = (pk > M1) ? pk : M1;           /* max */                 \
    M2 = (M2 < tmp) ? M2 : tmp;                   /* min */                 \
    M1 = (M1 < pk) ? M1 : pk;                     /* min */                 \
  }

  int cf = 0;
  #pragma unroll 1
  for (int c = 0; c < Cc; ++c) {
    const float* rcc = rcb + c * (Hh * Ww);
    #pragma unroll
    for (int ki = 0; ki < 5; ++ki) {
      #pragma unroll
      for (int kj = 0; kj < 5; ++kj) {
        float rc = rcc[ki * Ww + kj];
        uint32_t c1 = ctr1 + (uint32_t)cf;
        uint32_t bb1 = threefry_0_42_pre(c1);
        uint32_t bb2 = threefry_0_42_pre(c1 + 16588800u);
        SURR(bb1, rc, m1a, m2a)
        SURR(bb2, rc, m1b, m2b)
        ++cf;
      }
    }
  }
#undef SURR

  // Resolve: confident -> write spike; ambiguous -> enqueue for k_fix.
  float f1a = __uint_as_float(m1a & 0xFFFFFC00u);
  float f2a = __uint_as_float(m2a & 0xFFFFFC00u);
  float f1b = __uint_as_float(m1b & 0xFFFFFC00u);
  float f2b = __uint_as_float(m2b & 0xFFFFFC00u);
  constexpr float MARG = 1.0f + 0.0009765625f;  // 1 + 2^-10
  bool ca = (f1a <= 0.04f) && (f2a > f1a * MARG);
  bool cb = (f1b <= 0.04f) && (f2b > f1b * MARG);
  int sid2 = sid1 + 48 * NPIX;
  if (ca) {
    spikes[sid1] = (int)(m1a & 1023u);
  } else {
    int qi = atomicAdd(qcount, 1);
    if (qi < QCAP) queue[qi] = sid1;
    else spikes[sid1] = exact_argmax_serial(
             ctr1, input + (b * Cc) * (Hh * Ww) + x * Ww + y);
  }
  if (cb) {
    spikes[sid2] = (int)(m1b & 1023u);
  } else {
    int qi = atomicAdd(qcount, 1);
    if (qi < QCAP) queue[qi] = sid2;
    else spikes[sid2] = exact_argmax_serial(
             ctr1 + 16588800u, input + (b * Cc) * (Hh * Ww) + x * Ww + y);
  }
}

// One WAVE per queued (ambiguous) sample: 64 lanes split the 600 candidates,
// bit-exact ocml chain, then shuffle-reduce (max v, tie -> min cf) ==
// sequential first-max-wins (f32 equality is exact; lowest cf among equal
// maxima wins, matching the strict-> sequential scan).
__global__ __launch_bounds__(256) void k_fix(const int* __restrict__ qcount,
                                             const int* __restrict__ queue,
                                             const float* __restrict__ input,
                                             int* __restrict__ spikes) {
  int nq = *qcount;
  if (nq > QCAP) nq = QCAP;
  int gwid = (blockIdx.x * 256 + threadIdx.x) >> 6;
  int lane = threadIdx.x & 63;
  int nwaves = (gridDim.x * 256) >> 6;
  for (int qi = gwid; qi < nq; qi += nwaves) {
    int sid = queue[qi];
    int y = sid % OWt;
    int x = (sid / OWt) % OHt;
    int b = sid / (NPIX * TT);
    uint32_t base = (uint32_t)sid * 600u + 42u;
    const float* inb = input + (b * Cc) * (Hh * Ww) + x * Ww + y;
    float best = -1e30f;
    int bcf = 1024;
    for (int cf = lane; cf < CF; cf += 64) {
      int c = cf / 25;
      int r = cf - c * 25;
      int ki = r / 5;
      int kj = r - ki * 5;
      float v = exact_v(threefry_0_42_pre(base + (uint32_t)cf),
                        logf(inb[c * (Hh * Ww) + ki * Ww + kj]));
      if (v > best) { best = v; bcf = cf; }  // in-lane: ascending cf, strict >
    }
    #pragma unroll
    for (int off = 32; off > 0; off >>= 1) {
      float vo = __shfl_xor(best, off, 64);
      int co = __shfl_xor(bcf, off, 64);
      if (vo > best || (vo == best && co < bcf)) { best = vo; bcf = co; }
    }
    if (lane == 0) spikes[sid] = bcf;
  }
}

// One wave per pixel, 2 neurons per lane; 96 sequential normalized updates.
__global__ __launch_bounds__(256) void k_recur(
    const int* __restrict__ spikes, const float* __restrict__ weights,
    const float* __restrict__ eps_xy, const float* __restrict__ eps_t,
    const float* __restrict__ eps0p, const float* __restrict__ h_init,
    float* __restrict__ out) {
  int wid = blockIdx.x * 4 + (threadIdx.x >> 6);  // pixel id in [0, 18432)
  int lane = threadIdx.x & 63;
  int y = wid % OWt;
  int x = (wid / OWt) % OHt;
  int b = wid / NPIX;
  float g0 = h_init[lane];
  float g1 = h_init[lane + 64];
  float e0 = eps0p[0];
  const int* sp = spikes + (b * TT) * NPIX + x * OWt + y;
  const float* ex = eps_xy + (x * OWt + y) * 25;
  for (int t = 0; t < TT; ++t) {
    int s = sp[t * NPIX];  // wave-uniform
    const float* wr = weights + s * HN;
    float wg0 = wr[lane] * g0;
    float wg1 = wr[lane + 64] * g1;
    float sum = wg0 + wg1;
    #pragma unroll
    for (int off = 32; off > 0; off >>= 1) sum += __shfl_xor(sum, off, 64);
    float es = ex[s % 25] * (eps_t[t] * e0);  // eps * (et * eps0)
    float factor = es / sum;
    if (!__builtin_isfinite(factor)) factor = 0.0f;  // nan_to_num
    float d = 1.0f + es;
    g0 = (g0 + wg0 * factor) / d;
    g1 = (g1 + wg1 * factor) / d;
  }
  out[((b * HN + lane) * OHt + x) * OWt + y] = g0;
  out[((b * HN + lane + 64) * OHt + x) * OWt + y] = g1;
}

extern "C" void kernel_launch(void* const* d_in, const int* in_sizes, int n_in,
                              void* d_out, int out_size, void* d_ws, size_t ws_size,
                              hipStream_t stream) {
  const float* input   = (const float*)d_in[0];
  const float* eps_xy  = (const float*)d_in[1];
  const float* eps0    = (const float*)d_in[2];
  const float* eps_t   = (const float*)d_in[3];
  const float* weights = (const float*)d_in[4];
  const float* h_init  = (const float*)d_in[5];
  // d_in[6] = number_of_spikes (=96, hardcoded)

  float* rinc = (float*)d_ws;                                // 602,112 f32
  int* spikes = (int*)((char*)d_ws + NLOG * sizeof(float));  // 1,769,472 i32
  // Ambiguous queue lives in d_out's tail: k_fix consumes it BEFORE k_recur
  // (stream-ordered) and k_recur then overwrites all of d_out.
  int* outi = (int*)d_out;
  int* qcount = outi + (NOUT - 1);
  int* queue = outi + (NOUT - 1 - QCAP);

  k_rinc<<<(NLOG + 255) / 256, 256, 0, stream>>>(input, rinc, qcount);
  k_sample<<<(NSAMP / 2) / 256, 256, 0, stream>>>(rinc, input, spikes, qcount,
                                                  queue);
  k_fix<<<256, 256, 0, stream>>>(qcount, queue, input, spikes);
  k_recur<<<(Bn * NPIX) / 4, 256, 0, stream>>>(spikes, weights, eps_xy, eps_t,
                                               eps0, h_init, (float*)d_out);
}